// Round 19
// baseline (241.832 us; speedup 1.0000x reference)
//
#include <hip/hip_runtime.h>

#define N_NODES 100000
#define N_EDGES 3200000
#define N_GRAPHS 1024
#define NCLS 21
#define NBKT 782          // buckets of 128 nodes
#define CAP 4480          // padded bucket capacity (mean 4096, sigma 64 -> +6 sigma)
#define NB 512            // streaming blocks for binning
#define CHUNK 6250        // N_EDGES / NB
#define TROW 72           // LDS tile row stride in ushorts

typedef short s8v __attribute__((ext_vector_type(8)));
typedef float f4v __attribute__((ext_vector_type(4)));

__device__ __forceinline__ float bf2f(unsigned short u) {
    return __uint_as_float(((unsigned)u) << 16);
}
__device__ __forceinline__ unsigned short f2bf(float f) {
    unsigned u = __float_as_uint(f);
    unsigned r = 0x7fffu + ((u >> 16) & 1u);   // RNE
    return (unsigned short)((u + r) >> 16);
}
__device__ __forceinline__ float lo2f(unsigned w) { return __uint_as_float(w << 16); }
__device__ __forceinline__ float hi2f(unsigned w) { return __uint_as_float(w & 0xffff0000u); }

// ---- fused prep: wp pack (blocks 0-31), gstart (32-36), gcur init (37) ----
__global__ void k_prep(const float* __restrict__ W2l, const float* __restrict__ W2r,
                       unsigned short* __restrict__ wp,
                       const int* __restrict__ batch, int* __restrict__ gstart,
                       int* __restrict__ gcur) {
    if (blockIdx.x < 32) {
        int tid = blockIdx.x * 256 + threadIdx.x;   // 8192 total
        int frag = tid >> 9;
        int r = tid & 511;
        int L = r >> 3, j = r & 7;
        int kstep = frag >> 2, nt = frag & 3;
        int k = kstep * 32 + (L >> 4) * 8 + j;
        int n = nt * 16 + (L & 15);
        float val = (k < 64) ? W2l[k * 64 + n] : W2r[(k - 64) * 64 + n];
        wp[tid] = f2bf(val);
    } else if (blockIdx.x < 37) {
        int g = (blockIdx.x - 32) * 256 + threadIdx.x;
        if (g > N_GRAPHS) return;
        if (g == N_GRAPHS) { gstart[N_GRAPHS] = N_NODES; return; }
        int lo = 0, hi = N_NODES;
        while (lo < hi) { int m = (lo + hi) >> 1; if (batch[m] < g) lo = m + 1; else hi = m; }
        gstart[g] = lo;
    } else {
        for (int i = threadIdx.x; i < NBKT; i += 256) gcur[i] = i * CAP;
    }
}

// ---- two-pass bin, no LDS edge buffer: chunk stays L2-hot between passes ----
// pass1: per-WAVE hist replicas (4x less contention); reserve per wave-PAIR
// sub-runs; pass2: re-read src/dst, scatter via per-pair cursor replicas.
__global__ __launch_bounds__(256) void k_binone(const int* __restrict__ src,
                                                const int* __restrict__ dst,
                                                int* __restrict__ gcur,
                                                unsigned int* __restrict__ bins) {
    __shared__ int lh[4][NBKT];     // 12.5 KB
    __shared__ int lcur[2][NBKT];   // 6.3 KB
    int t = threadIdx.x;
    int wid = t >> 6;
    for (int i = t; i < 4 * NBKT; i += 256) ((int*)lh)[i] = 0;
    __syncthreads();
    const int2* d2 = (const int2*)(dst + blockIdx.x * CHUNK);
    for (int i = t; i < CHUNK / 2; i += 256) {
        int2 d = d2[i];
        atomicAdd(&lh[wid][d.x >> 7], 1);
        atomicAdd(&lh[wid][d.y >> 7], 1);
    }
    __syncthreads();
    for (int i = t; i < NBKT; i += 256) {
        int c0 = lh[0][i], c1 = lh[1][i], c2 = lh[2][i], c3 = lh[3][i];
        int p0 = c0 + c1;
        int tot = p0 + c2 + c3;
        int base = atomicAdd(&gcur[i], tot);   // one global atomic per bucket
        lcur[0][i] = base;                     // waves 0,1 region
        lcur[1][i] = base + p0;                // waves 2,3 region
    }
    __syncthreads();
    const int2* s2 = (const int2*)(src + blockIdx.x * CHUNK);
    int half = wid >> 1;
    for (int i = t; i < CHUNK / 2; i += 256) {   // same elements as pass 1
        int2 s = s2[i];
        int2 d = d2[i];
        int b0 = d.x >> 7;
        int p0 = atomicAdd(&lcur[half][b0], 1);
        if (p0 < (b0 + 1) * CAP)
            bins[p0] = ((unsigned)s.x << 7) | (unsigned)(d.x & 127);
        int b1 = d.y >> 7;
        int p1 = atomicAdd(&lcur[half][b1], 1);
        if (p1 < (b1 + 1) * CAP)
            bins[p1] = ((unsigned)s.y << 7) | (unsigned)(d.y & 127);
    }
}

// ---- per-bucket (128 nodes): slurp -> hist -> scan -> row/deg + CSR + layer-1 ----
__global__ __launch_bounds__(256) void k_build(
    const int* __restrict__ gcur, unsigned int* __restrict__ bins,
    int* __restrict__ row, unsigned short* __restrict__ deg,
    const float* __restrict__ x,
    const float* __restrict__ W1l, const float* __restrict__ b1,
    const float* __restrict__ W1r, unsigned short* __restrict__ h1b) {
    __shared__ unsigned int ebuf[CAP];   // 17.9 KB
    __shared__ int hist[128];
    __shared__ int curs[128];
    __shared__ int lds[128];
    __shared__ float t1[128];
    int k = blockIdx.x, t = threadIdx.x;
    int e0 = k * CAP;
    int cnt = min(gcur[k] - e0, CAP);
    if (t < 128) { hist[t] = 0; t1[t] = 0.0f; }
    __syncthreads();
    for (int i = t; i < cnt; i += 256) {
        unsigned p = bins[e0 + i];
        ebuf[i] = p;
        atomicAdd(&hist[p & 127u], 1);
    }
    __syncthreads();
    if (t < 128) lds[t] = hist[t];
    __syncthreads();
    for (int off = 1; off < 128; off <<= 1) {
        int cur = (t < 128) ? lds[t] : 0;
        int add = (t < 128 && t >= off) ? lds[t - off] : 0;
        __syncthreads();
        if (t < 128) lds[t] = cur + add;
        __syncthreads();
    }
    if (t < 128) {
        int run = e0 + lds[t] - hist[t];
        curs[t] = run;
        int n = k * 128 + t;
        if (n < N_NODES) { row[n] = run; deg[n] = (unsigned short)hist[t]; }
    }
    __syncthreads();
    for (int i = t; i < cnt; i += 256) {
        unsigned p = ebuf[i];
        int slot = (int)(p & 127u);
        int pos = atomicAdd(&curs[slot], 1);
        bins[pos] = p >> 7;
        atomicAdd(&t1[slot], x[p >> 7]);
    }
    __syncthreads();
    for (int i = t; i < 128 * 64; i += 256) {
        int slot = i >> 6, f = i & 63;
        int n = k * 128 + slot;
        if (n >= N_NODES) break;
        float a = t1[slot] / fmaxf((float)hist[slot], 1.0f);
        float v = a * W1l[f] + b1[f] + x[n] * W1r[f];
        h1b[(size_t)n * 64 + f] = f2bf(fmaxf(v, 0.0f));
    }
}

// ---- layer 2 FUSED: gather (per node) -> LDS tile -> MFMA GEMV -> h2b ----
__global__ __launch_bounds__(256) void k_l2f(
    const int* __restrict__ row, const unsigned short* __restrict__ deg,
    const unsigned int* __restrict__ csr,
    const unsigned short* __restrict__ h1b,
    const unsigned short* __restrict__ wp, const float* __restrict__ b2,
    unsigned short* __restrict__ h2b) {
    __shared__ unsigned short tile[4][16 * TROW];   // 9 KB
    int wid = threadIdx.x >> 6;
    int w = blockIdx.x * 4 + wid;
    if (w >= N_NODES / 16) return;
    int L = threadIdx.x & 63;
    int fo = L & 7;
    int es = L >> 3;
    int fown = fo * 8 + es;
    unsigned short* tw = tile[wid];

    for (int t = 0; t < 16; t++) {
        int n = w * 16 + t;
        int r0 = row[n];
        int dn = (int)deg[n];
        int r1 = r0 + dn;
        float a0 = 0.f, a1 = 0.f, a2 = 0.f, a3 = 0.f,
              a4 = 0.f, a5 = 0.f, a6 = 0.f, a7 = 0.f;
        int base = r0;
        for (; base + 32 <= r1; base += 32) {
            int sA = (int)csr[base + es];
            int sB = (int)csr[base + 8 + es];
            int sC = (int)csr[base + 16 + es];
            int sD = (int)csr[base + 24 + es];
            uint4 dA = *(const uint4*)(h1b + (size_t)sA * 64 + fo * 8);
            uint4 dB = *(const uint4*)(h1b + (size_t)sB * 64 + fo * 8);
            uint4 dC = *(const uint4*)(h1b + (size_t)sC * 64 + fo * 8);
            uint4 dD = *(const uint4*)(h1b + (size_t)sD * 64 + fo * 8);
            a0 += lo2f(dA.x); a1 += hi2f(dA.x); a2 += lo2f(dA.y); a3 += hi2f(dA.y);
            a4 += lo2f(dA.z); a5 += hi2f(dA.z); a6 += lo2f(dA.w); a7 += hi2f(dA.w);
            a0 += lo2f(dB.x); a1 += hi2f(dB.x); a2 += lo2f(dB.y); a3 += hi2f(dB.y);
            a4 += lo2f(dB.z); a5 += hi2f(dB.z); a6 += lo2f(dB.w); a7 += hi2f(dB.w);
            a0 += lo2f(dC.x); a1 += hi2f(dC.x); a2 += lo2f(dC.y); a3 += hi2f(dC.y);
            a4 += lo2f(dC.z); a5 += hi2f(dC.z); a6 += lo2f(dC.w); a7 += hi2f(dC.w);
            a0 += lo2f(dD.x); a1 += hi2f(dD.x); a2 += lo2f(dD.y); a3 += hi2f(dD.y);
            a4 += lo2f(dD.z); a5 += hi2f(dD.z); a6 += lo2f(dD.w); a7 += hi2f(dD.w);
        }
        for (; base + 16 <= r1; base += 16) {
            int sA = (int)csr[base + es];
            int sB = (int)csr[base + 8 + es];
            uint4 dA = *(const uint4*)(h1b + (size_t)sA * 64 + fo * 8);
            uint4 dB = *(const uint4*)(h1b + (size_t)sB * 64 + fo * 8);
            a0 += lo2f(dA.x); a1 += hi2f(dA.x); a2 += lo2f(dA.y); a3 += hi2f(dA.y);
            a4 += lo2f(dA.z); a5 += hi2f(dA.z); a6 += lo2f(dA.w); a7 += hi2f(dA.w);
            a0 += lo2f(dB.x); a1 += hi2f(dB.x); a2 += lo2f(dB.y); a3 += hi2f(dB.y);
            a4 += lo2f(dB.z); a5 += hi2f(dB.z); a6 += lo2f(dB.w); a7 += hi2f(dB.w);
        }
        for (; base < r1; base += 8) {
            int e = base + es;
            bool act = e < r1;
            int sA = (int)csr[act ? e : r1 - 1];
            uint4 d = *(const uint4*)(h1b + (size_t)sA * 64 + fo * 8);
            unsigned m = act ? 0xffffffffu : 0u;
            d.x &= m; d.y &= m; d.z &= m; d.w &= m;
            a0 += lo2f(d.x); a1 += hi2f(d.x); a2 += lo2f(d.y); a3 += hi2f(d.y);
            a4 += lo2f(d.z); a5 += hi2f(d.z); a6 += lo2f(d.w); a7 += hi2f(d.w);
        }
        {
            bool hi = (es & 4) != 0;
            float s0 = hi ? a0 : a4, s1 = hi ? a1 : a5, s2 = hi ? a2 : a6, s3 = hi ? a3 : a7;
            float r0v = __shfl_xor(s0, 32, 64);
            float r1v = __shfl_xor(s1, 32, 64);
            float r2v = __shfl_xor(s2, 32, 64);
            float r3v = __shfl_xor(s3, 32, 64);
            a0 = (hi ? a4 : a0) + r0v;
            a1 = (hi ? a5 : a1) + r1v;
            a2 = (hi ? a6 : a2) + r2v;
            a3 = (hi ? a7 : a3) + r3v;
        }
        {
            bool hi = (es & 2) != 0;
            float s0 = hi ? a0 : a2, s1 = hi ? a1 : a3;
            float r0v = __shfl_xor(s0, 16, 64);
            float r1v = __shfl_xor(s1, 16, 64);
            a0 = (hi ? a2 : a0) + r0v;
            a1 = (hi ? a3 : a1) + r1v;
        }
        {
            bool hi = (es & 1) != 0;
            float s0 = hi ? a0 : a1;
            float r0v = __shfl_xor(s0, 8, 64);
            a0 = (hi ? a1 : a0) + r0v;
        }
        float inv = 1.0f / fmaxf((float)dn, 1.0f);
        tw[t * TROW + fown] = f2bf(a0 * inv);
    }

    int m = L & 15, q = L >> 4;
    int nrow = w * 16 + m;

    const s8v a0 = *(const s8v*)(tw + m * TROW + q * 8);
    const s8v a1 = *(const s8v*)(tw + m * TROW + 32 + q * 8);
    const s8v a2 = *(const s8v*)(h1b + (size_t)nrow * 64 + q * 8);
    const s8v a3 = *(const s8v*)(h1b + (size_t)nrow * 64 + 32 + q * 8);

#define LOADB(i) s8v B##i = *(const s8v*)(wp + (i) * 512 + L * 8)
    LOADB(0); LOADB(1); LOADB(2); LOADB(3);
    LOADB(4); LOADB(5); LOADB(6); LOADB(7);
    LOADB(8); LOADB(9); LOADB(10); LOADB(11);
    LOADB(12); LOADB(13); LOADB(14); LOADB(15);
#undef LOADB

    f4v acc0 = {0.f, 0.f, 0.f, 0.f}, acc1 = acc0, acc2 = acc0, acc3 = acc0;
    acc0 = __builtin_amdgcn_mfma_f32_16x16x32_bf16(a0, B0,  acc0, 0, 0, 0);
    acc0 = __builtin_amdgcn_mfma_f32_16x16x32_bf16(a1, B4,  acc0, 0, 0, 0);
    acc0 = __builtin_amdgcn_mfma_f32_16x16x32_bf16(a2, B8,  acc0, 0, 0, 0);
    acc0 = __builtin_amdgcn_mfma_f32_16x16x32_bf16(a3, B12, acc0, 0, 0, 0);
    acc1 = __builtin_amdgcn_mfma_f32_16x16x32_bf16(a0, B1,  acc1, 0, 0, 0);
    acc1 = __builtin_amdgcn_mfma_f32_16x16x32_bf16(a1, B5,  acc1, 0, 0, 0);
    acc1 = __builtin_amdgcn_mfma_f32_16x16x32_bf16(a2, B9,  acc1, 0, 0, 0);
    acc1 = __builtin_amdgcn_mfma_f32_16x16x32_bf16(a3, B13, acc1, 0, 0, 0);
    acc2 = __builtin_amdgcn_mfma_f32_16x16x32_bf16(a0, B2,  acc2, 0, 0, 0);
    acc2 = __builtin_amdgcn_mfma_f32_16x16x32_bf16(a1, B6,  acc2, 0, 0, 0);
    acc2 = __builtin_amdgcn_mfma_f32_16x16x32_bf16(a2, B10, acc2, 0, 0, 0);
    acc2 = __builtin_amdgcn_mfma_f32_16x16x32_bf16(a3, B14, acc2, 0, 0, 0);
    acc3 = __builtin_amdgcn_mfma_f32_16x16x32_bf16(a0, B3,  acc3, 0, 0, 0);
    acc3 = __builtin_amdgcn_mfma_f32_16x16x32_bf16(a1, B7,  acc3, 0, 0, 0);
    acc3 = __builtin_amdgcn_mfma_f32_16x16x32_bf16(a2, B11, acc3, 0, 0, 0);
    acc3 = __builtin_amdgcn_mfma_f32_16x16x32_bf16(a3, B15, acc3, 0, 0, 0);

    int fcol = L & 15;
    float bia0 = b2[fcol], bia1 = b2[16 + fcol], bia2 = b2[32 + fcol], bia3 = b2[48 + fcol];
    int rbase = w * 16 + q * 4;
#pragma unroll
    for (int r = 0; r < 4; r++) {
        size_t o = (size_t)(rbase + r) * 64 + fcol;
        h2b[o]      = f2bf(fmaxf(acc0[r] + bia0, 0.0f));
        h2b[o + 16] = f2bf(fmaxf(acc1[r] + bia1, 0.0f));
        h2b[o + 32] = f2bf(fmaxf(acc2[r] + bia2, 0.0f));
        h2b[o + 48] = f2bf(fmaxf(acc3[r] + bia3, 0.0f));
    }
}

// ---- head: block per graph — pool h2 rows + classify ----
__global__ __launch_bounds__(256) void k_head(
    const unsigned short* __restrict__ h2b, const int* __restrict__ gstart,
    const float* __restrict__ Wc, const float* __restrict__ bc,
    float* __restrict__ out) {
    __shared__ float part[4][64];
    __shared__ float rowv[64];
    int g = blockIdx.x;
    int wid = threadIdx.x >> 6;
    int f = threadIdx.x & 63;
    int ns = gstart[g], ne = gstart[g + 1];
    float s = 0.0f;
    int n = ns + wid;
    for (; n + 12 < ne; n += 16) {
        float v0 = bf2f(h2b[(size_t)(n)      * 64 + f]);
        float v1 = bf2f(h2b[(size_t)(n + 4)  * 64 + f]);
        float v2 = bf2f(h2b[(size_t)(n + 8)  * 64 + f]);
        float v3 = bf2f(h2b[(size_t)(n + 12) * 64 + f]);
        s += (v0 + v1) + (v2 + v3);
    }
    for (; n < ne; n += 4) s += bf2f(h2b[(size_t)n * 64 + f]);
    part[wid][f] = s;
    __syncthreads();
    if (threadIdx.x < 64) {
        float tot = part[0][f] + part[1][f] + part[2][f] + part[3][f];
        rowv[f] = tot / fmaxf((float)(ne - ns), 1.0f);
    }
    __syncthreads();
    if (threadIdx.x < NCLS) {
        float acc = bc[threadIdx.x];
#pragma unroll
        for (int kk = 0; kk < 64; kk++) acc += rowv[kk] * Wc[kk * NCLS + threadIdx.x];
        out[g * NCLS + threadIdx.x] = acc;
    }
}

extern "C" void kernel_launch(void* const* d_in, const int* in_sizes, int n_in,
                              void* d_out, int out_size, void* d_ws, size_t ws_size,
                              hipStream_t stream) {
    const float* x     = (const float*)d_in[0];
    const int*   eidx  = (const int*)d_in[1];
    const int*   batch = (const int*)d_in[2];
    const float* W1l   = (const float*)d_in[3];
    const float* b1    = (const float*)d_in[4];
    const float* W1r   = (const float*)d_in[5];
    const float* W2l   = (const float*)d_in[6];
    const float* b2    = (const float*)d_in[7];
    const float* W2r   = (const float*)d_in[8];
    const float* Wc    = (const float*)d_in[9];
    const float* bc    = (const float*)d_in[10];
    float* out = (float*)d_out;

    const int* src = eidx;
    const int* dst = eidx + N_EDGES;

    // workspace ≈ 40.3 MB (R16/R17 passed with this footprint)
    char* p = (char*)d_ws;
    unsigned int* bins  = (unsigned int*)p;     p += (size_t)NBKT * CAP * 4;     // 14.0 MB
    unsigned short* h1b = (unsigned short*)p;   p += (size_t)N_NODES * 64 * 2;   // 12.8 MB
    unsigned short* h2b = (unsigned short*)p;   p += (size_t)N_NODES * 64 * 2;   // 12.8 MB
    int* row   = (int*)p;                       p += (size_t)(N_NODES + 1) * 4;  // 0.40 MB
    unsigned short* deg = (unsigned short*)p;   p += (size_t)N_NODES * 2;        // 0.20 MB
    int* gcur  = (int*)p;                       p += NBKT * 4;
    int* gstart= (int*)p;                       p += (N_GRAPHS + 1) * 4;
    unsigned short* wp = (unsigned short*)p;    p += 8192 * 2;                   // 16 KB

    k_prep  <<<38, 256, 0, stream>>>(W2l, W2r, wp, batch, gstart, gcur);
    k_binone<<<NB, 256, 0, stream>>>(src, dst, gcur, bins);
    k_build <<<NBKT, 256, 0, stream>>>(gcur, bins, row, deg, x, W1l, b1, W1r, h1b);
    k_l2f   <<<(N_NODES / 16 + 3) / 4, 256, 0, stream>>>(row, deg, bins, h1b, wp, b2, h2b);
    k_head  <<<N_GRAPHS, 256, 0, stream>>>(h2b, gstart, Wc, bc, out);
}